// Round 3
// baseline (197.648 us; speedup 1.0000x reference)
//
#include <hip/hip_runtime.h>
#include <hip/hip_bf16.h>
#include <cstdint>
#include <cstddef>

#define BDIM 64
#define SDIM 512
#define HDIM 1024
#define MTOT (BDIM * SDIM)  // 32768

typedef __attribute__((ext_vector_type(8))) short short8;
typedef __attribute__((ext_vector_type(4))) float f32x4;

// HW packed f32->bf16 RNE convert.
__device__ __forceinline__ unsigned int cvt2(float a, float b) {
  unsigned int r;
  asm("v_cvt_pk_bf16_f32 %0, %1, %2" : "=v"(r) : "v"(a), "v"(b));
  return r;
}

__device__ __forceinline__ void gld_lds16(const void* g, void* l) {
  __builtin_amdgcn_global_load_lds(
      (const __attribute__((address_space(1))) unsigned int*)g,
      (__attribute__((address_space(3))) unsigned int*)l, 16, 0, 0);
}

// W2 = W[:, H:2H] -> bf16, tile-major + XOR-swizzled layout in ws (as r2).
__global__ __launch_bounds__(256) void prep_w2_kernel(const float* __restrict__ W,
                                                      char* __restrict__ w2s) {
  const int n = blockIdx.x * 2 + (threadIdx.x >> 7);
  const int g = threadIdx.x & 127;
  const int kt = g >> 3, gi = g & 7;
  const float* src = W + (size_t)n * 2048 + 1024 + g * 8;
  const float4 f0 = *reinterpret_cast<const float4*>(src);
  const float4 f1 = *reinterpret_cast<const float4*>(src + 4);
  uint4 u = make_uint4(cvt2(f0.x, f0.y), cvt2(f0.z, f0.w),
                       cvt2(f1.x, f1.y), cvt2(f1.z, f1.w));
  const int nblk = n >> 7, row = n & 127;
  const size_t off = ((size_t)(nblk * 16 + kt) * 128 + row) * 128 +
                     (size_t)(gi ^ (row & 7)) * 16;
  *reinterpret_cast<uint4*>(w2s + off) = u;
}

// A[b,h] = hidden[b,:] . W[h, 0:H] + bias[h]   (f32)
__global__ __launch_bounds__(256) void compute_a_kernel(const float* __restrict__ hidden,
                                                        const float* __restrict__ W,
                                                        const float* __restrict__ bias,
                                                        float* __restrict__ A) {
  const int hc = blockIdx.x;
  const int b  = blockIdx.y;
  const int t  = threadIdx.x;
  __shared__ float hl[HDIM];
  *reinterpret_cast<float4*>(&hl[t * 4]) =
      *reinterpret_cast<const float4*>(hidden + (size_t)b * HDIM + t * 4);
  __syncthreads();
  const int h = hc * 256 + t;
  const float* wr = W + (size_t)h * 2048;
  float acc = bias[h];
  for (int k = 0; k < HDIM; k += 4) {
    const float4 wv = *reinterpret_cast<const float4*>(wr + k);
    acc += wv.x * hl[k] + wv.y * hl[k + 1] + wv.z * hl[k + 2] + wv.w * hl[k + 3];
  }
  A[(size_t)b * HDIM + h] = acc;
}

// Main GEMM (128x128 tile, BK=64) with 1-barrier/step double-buffered pipeline:
//   regs hold A-tile(t+1) f32 (issued during MFMA(t)); gld_lds B(t+1) -> other buf.
__global__ __launch_bounds__(256) void gemm_scores_kernel(const float* __restrict__ enc,
                                                          const char* __restrict__ w2s,
                                                          const float* __restrict__ A,
                                                          const float* __restrict__ v,
                                                          float* __restrict__ sp) {
  __shared__ unsigned short As[2][128][64];  // 2 x 16 KB, XOR-swizzled granules
  __shared__ unsigned short Bs[2][128][64];  // 2 x 16 KB, XOR-swizzled granules

  const int lg = (int)((blockIdx.x & 7) * 256 + (blockIdx.x >> 3));
  const int nblk = lg & 7;
  const int mstrip = lg >> 3;
  const int m0 = mstrip * 128;
  const int n0 = nblk * 128;
  const int b = m0 >> 9;

  const int tid = threadIdx.x;
  const int w = tid >> 6, l = tid & 63;
  const int wm = w >> 1, wn = w & 1;
  const int lr = l & 15, lk = l >> 4;

  // Per-thread A staging geometry (row/granule fixed per i).
  const int row0 = tid >> 3, g0 = tid & 7;  // i=0; i adds 32 rows

  f32x4 zero = {0.f, 0.f, 0.f, 0.f};
  f32x4 acc[4][4];
#pragma unroll
  for (int fm = 0; fm < 4; ++fm)
#pragma unroll
    for (int fn = 0; fn < 4; ++fn) acc[fm][fn] = zero;

  const char* wtile_base = w2s + ((size_t)nblk * 16) * 16384;
  const float* encb = enc + (size_t)m0 * HDIM;

  float4 pf[8];

  // ---- prologue: issue A(0) loads and B(0) DMA ----
#pragma unroll
  for (int i = 0; i < 4; ++i) {
    const float* s = encb + (size_t)(row0 + i * 32) * HDIM + g0 * 8;
    pf[2 * i]     = *reinterpret_cast<const float4*>(s);
    pf[2 * i + 1] = *reinterpret_cast<const float4*>(s + 4);
  }
  {
    const char* wtile = wtile_base;
    char* BsB = reinterpret_cast<char*>(&Bs[0][0][0]);
#pragma unroll
    for (int c = 0; c < 4; ++c) {
      const int off = c * 4096 + w * 1024;
      gld_lds16(wtile + off + l * 16, BsB + off);
    }
  }

  for (int t = 0; t < 16; ++t) {
    const int cur = t & 1;
    // ---- convert + write A(t) to swizzled LDS slots ----
    {
      char* dst = reinterpret_cast<char*>(&As[cur][0][0]);
#pragma unroll
      for (int i = 0; i < 4; ++i) {
        const int row = row0 + i * 32;
        uint4 u = make_uint4(cvt2(pf[2 * i].x, pf[2 * i].y),
                             cvt2(pf[2 * i].z, pf[2 * i].w),
                             cvt2(pf[2 * i + 1].x, pf[2 * i + 1].y),
                             cvt2(pf[2 * i + 1].z, pf[2 * i + 1].w));
        *reinterpret_cast<uint4*>(dst + row * 128 + (g0 ^ (row & 7)) * 16) = u;
      }
    }
    __syncthreads();  // A(t)/B(t) visible; all waves done with buffers (t+1)&1

    // ---- issue next-tile loads during this tile's MFMA phase ----
    if (t < 15) {
      const float* encn = encb + (t + 1) * 64;
#pragma unroll
      for (int i = 0; i < 4; ++i) {
        const float* s = encn + (size_t)(row0 + i * 32) * HDIM + g0 * 8;
        pf[2 * i]     = *reinterpret_cast<const float4*>(s);
        pf[2 * i + 1] = *reinterpret_cast<const float4*>(s + 4);
      }
      const char* wtile = wtile_base + (size_t)(t + 1) * 16384;
      char* BsB = reinterpret_cast<char*>(&Bs[(t + 1) & 1][0][0]);
#pragma unroll
      for (int c = 0; c < 4; ++c) {
        const int off = c * 4096 + w * 1024;
        gld_lds16(wtile + off + l * 16, BsB + off);
      }
    }

    // ---- MFMA on tile t ----
    const char* AsB = reinterpret_cast<const char*>(&As[cur][0][0]);
    const char* BsB = reinterpret_cast<const char*>(&Bs[cur][0][0]);
#pragma unroll
    for (int ks = 0; ks < 2; ++ks) {
      short8 af[4], bfr[4];
#pragma unroll
      for (int f = 0; f < 4; ++f) {
        const int ra = wm * 64 + f * 16 + lr;
        const int ga = (ks * 4 + lk) ^ (ra & 7);
        af[f] = *reinterpret_cast<const short8*>(AsB + ra * 128 + ga * 16);
        const int rb = wn * 64 + f * 16 + lr;
        const int gb = (ks * 4 + lk) ^ (rb & 7);
        bfr[f] = *reinterpret_cast<const short8*>(BsB + rb * 128 + gb * 16);
      }
#pragma unroll
      for (int fm = 0; fm < 4; ++fm)
#pragma unroll
        for (int fn = 0; fn < 4; ++fn)
          acc[fm][fn] = __builtin_amdgcn_mfma_f32_16x16x32_bf16(af[fm], bfr[fn], acc[fm][fn], 0, 0, 0);
    }
  }

  // ---- Epilogue: e = tanh(C + A), dot with v, per-row reduce ----
  const float* Ab = A + (size_t)b * HDIM + n0;
  const float* vb = v + n0;
  float a_n[4], v_n[4];
#pragma unroll
  for (int fn = 0; fn < 4; ++fn) {
    const int n = wn * 64 + fn * 16 + lr;
    a_n[fn] = Ab[n];
    v_n[fn] = vb[n];
  }
  float part[4][4];
#pragma unroll
  for (int fm = 0; fm < 4; ++fm) {
#pragma unroll
    for (int r = 0; r < 4; ++r) {
      float s = 0.f;
#pragma unroll
      for (int fn = 0; fn < 4; ++fn)
        s += v_n[fn] * tanhf(acc[fm][fn][r] + a_n[fn]);
      s += __shfl_xor(s, 1);
      s += __shfl_xor(s, 2);
      s += __shfl_xor(s, 4);
      s += __shfl_xor(s, 8);
      part[fm][r] = s;
    }
  }
  __syncthreads();
  float* red = reinterpret_cast<float*>(&As[0][0][0]);
  if (wn == 0 && lr == 0) {
#pragma unroll
    for (int fm = 0; fm < 4; ++fm)
#pragma unroll
      for (int r = 0; r < 4; ++r)
        red[wm * 64 + fm * 16 + lk * 4 + r] = part[fm][r];
  }
  __syncthreads();
  if (wn == 1 && lr == 0) {
#pragma unroll
    for (int fm = 0; fm < 4; ++fm)
#pragma unroll
      for (int r = 0; r < 4; ++r)
        red[wm * 64 + fm * 16 + lk * 4 + r] += part[fm][r];
  }
  __syncthreads();
  if (tid < 128) sp[(size_t)nblk * MTOT + m0 + tid] = red[tid];
}

// scores[b,s] = sum of 8 partials; softmax over s per b.
__global__ __launch_bounds__(512) void softmax_kernel(const float* __restrict__ sp,
                                                      float* __restrict__ wts) {
  const int b = blockIdx.x, s = threadIdx.x;
  float sc = 0.f;
#pragma unroll
  for (int j = 0; j < 8; ++j) sc += sp[(size_t)j * MTOT + b * SDIM + s];
  float m = sc;
#pragma unroll
  for (int d = 1; d < 64; d <<= 1) m = fmaxf(m, __shfl_xor(m, d));
  __shared__ float redm[8], reds[8];
  if ((s & 63) == 0) redm[s >> 6] = m;
  __syncthreads();
  m = redm[0];
#pragma unroll
  for (int j = 1; j < 8; ++j) m = fmaxf(m, redm[j]);
  const float e = expf(sc - m);
  float sum = e;
#pragma unroll
  for (int d = 1; d < 64; d <<= 1) sum += __shfl_xor(sum, d);
  if ((s & 63) == 0) reds[s >> 6] = sum;
  __syncthreads();
  float tot = 0.f;
#pragma unroll
  for (int j = 0; j < 8; ++j) tot += reds[j];
  wts[(size_t)b * SDIM + s] = e / tot;
}

// context[b,h] = sum_s w[b,s] * enc[b,s,h]
__global__ __launch_bounds__(256) void context_kernel(const float* __restrict__ enc,
                                                      const float* __restrict__ wts,
                                                      float* __restrict__ ctx) {
  const int hc = blockIdx.x;
  const int b  = blockIdx.y;
  const int t  = threadIdx.x;
  __shared__ float wl[SDIM];
  wl[t] = wts[(size_t)b * SDIM + t];
  wl[t + 256] = wts[(size_t)b * SDIM + 256 + t];
  __syncthreads();
  const int h = hc * 256 + t;
  const float* e0 = enc + (size_t)b * SDIM * HDIM + h;
  float acc0 = 0.f, acc1 = 0.f;
  for (int s = 0; s < SDIM; s += 2) {
    acc0 += wl[s] * e0[(size_t)s * HDIM];
    acc1 += wl[s + 1] * e0[(size_t)(s + 1) * HDIM];
  }
  ctx[(size_t)b * HDIM + h] = acc0 + acc1;
}

extern "C" void kernel_launch(void* const* d_in, const int* in_sizes, int n_in,
                              void* d_out, int out_size, void* d_ws, size_t ws_size,
                              hipStream_t stream) {
  const float* hidden = (const float*)d_in[0];
  const float* enc    = (const float*)d_in[1];
  const float* W      = (const float*)d_in[2];
  const float* bias   = (const float*)d_in[3];
  const float* v      = (const float*)d_in[4];

  float* ctx = (float*)d_out;                // [64*1024] context
  float* wts = (float*)d_out + BDIM * HDIM;  // [64*512] attention weights

  char* ws = (char*)d_ws;
  char* w2s = ws;                                                    // 2 MB swizzled tiles
  float* A  = (float*)(ws + (size_t)2 * 1024 * 1024);                // 256 KB
  float* sp = (float*)(ws + (size_t)2 * 1024 * 1024 + 256 * 1024);   // 1 MB

  hipLaunchKernelGGL(prep_w2_kernel, dim3(512), dim3(256), 0, stream, W, w2s);
  hipLaunchKernelGGL(compute_a_kernel, dim3(4, 64), dim3(256), 0, stream, hidden, W, bias, A);
  hipLaunchKernelGGL(gemm_scores_kernel, dim3(2048), dim3(256), 0, stream, enc, w2s, A, v, sp);
  hipLaunchKernelGGL(softmax_kernel, dim3(64), dim3(512), 0, stream, sp, wts);
  hipLaunchKernelGGL(context_kernel, dim3(4, 64), dim3(256), 0, stream, enc, wts, ctx);
}

// Round 4
// 197.326 us; speedup vs baseline: 1.0016x; 1.0016x over previous
//
#include <hip/hip_runtime.h>
#include <hip/hip_bf16.h>
#include <cstdint>
#include <cstddef>

#define BDIM 64
#define SDIM 512
#define HDIM 1024
#define MTOT (BDIM * SDIM)  // 32768

typedef __attribute__((ext_vector_type(8))) short short8;
typedef __attribute__((ext_vector_type(4))) float f32x4;

// HW packed f32->bf16 RNE convert.
__device__ __forceinline__ unsigned int cvt2(float a, float b) {
  unsigned int r;
  asm("v_cvt_pk_bf16_f32 %0, %1, %2" : "=v"(r) : "v"(a), "v"(b));
  return r;
}

__device__ __forceinline__ void gld_lds16(const void* g, void* l) {
  __builtin_amdgcn_global_load_lds(
      (const __attribute__((address_space(1))) unsigned int*)g,
      (__attribute__((address_space(3))) unsigned int*)l, 16, 0, 0);
}

// ---------------- prep: W2 -> swizzled bf16 tiles (unchanged) ----------------
__global__ __launch_bounds__(256) void prep_w2_kernel(const float* __restrict__ W,
                                                      char* __restrict__ w2s) {
  const int n = blockIdx.x * 2 + (threadIdx.x >> 7);
  const int g = threadIdx.x & 127;
  const int kt = g >> 3, gi = g & 7;
  const float* src = W + (size_t)n * 2048 + 1024 + g * 8;
  const float4 f0 = *reinterpret_cast<const float4*>(src);
  const float4 f1 = *reinterpret_cast<const float4*>(src + 4);
  uint4 u = make_uint4(cvt2(f0.x, f0.y), cvt2(f0.z, f0.w),
                       cvt2(f1.x, f1.y), cvt2(f1.z, f1.w));
  const int nblk = n >> 7, row = n & 127;
  const size_t off = ((size_t)(nblk * 16 + kt) * 128 + row) * 128 +
                     (size_t)(gi ^ (row & 7)) * 16;
  *reinterpret_cast<uint4*>(w2s + off) = u;
}

// ---------------- prep: enc f32 -> swizzled bf16 tiles (NEW) ----------------
// Tile (mstrip, kt): 128 rows x 8 granules(16B), granule g of row r at slot
// g ^ (r&7). Tiles contiguous, ordered (mstrip*16 + kt) * 16384 bytes.
__global__ __launch_bounds__(256) void prep_enc_kernel(const float* __restrict__ enc,
                                                       char* __restrict__ enc16) {
  const int kt = blockIdx.x;      // 0..15
  const int mstrip = blockIdx.y;  // 0..255
  const int tid = threadIdx.x;
  const float* src0 = enc + (size_t)mstrip * 128 * HDIM + kt * 64;
  char* tile = enc16 + (size_t)(mstrip * 16 + kt) * 16384;
#pragma unroll
  for (int i = 0; i < 4; ++i) {
    const int j = tid + i * 256;
    const int row = j >> 3, g = j & 7;
    const float* s = src0 + (size_t)row * HDIM + g * 8;
    const float4 f0 = *reinterpret_cast<const float4*>(s);
    const float4 f1 = *reinterpret_cast<const float4*>(s + 4);
    uint4 u = make_uint4(cvt2(f0.x, f0.y), cvt2(f0.z, f0.w),
                         cvt2(f1.x, f1.y), cvt2(f1.z, f1.w));
    *reinterpret_cast<uint4*>(tile + row * 128 + (g ^ (row & 7)) * 16) = u;
  }
}

// ---------------- A[b,h] = hidden.W1 + bias (unchanged) ----------------
__global__ __launch_bounds__(256) void compute_a_kernel(const float* __restrict__ hidden,
                                                        const float* __restrict__ W,
                                                        const float* __restrict__ bias,
                                                        float* __restrict__ A) {
  const int hc = blockIdx.x;
  const int b  = blockIdx.y;
  const int t  = threadIdx.x;
  __shared__ float hl[HDIM];
  *reinterpret_cast<float4*>(&hl[t * 4]) =
      *reinterpret_cast<const float4*>(hidden + (size_t)b * HDIM + t * 4);
  __syncthreads();
  const int h = hc * 256 + t;
  const float* wr = W + (size_t)h * 2048;
  float acc = bias[h];
  for (int k = 0; k < HDIM; k += 4) {
    const float4 wv = *reinterpret_cast<const float4*>(wr + k);
    acc += wv.x * hl[k] + wv.y * hl[k + 1] + wv.z * hl[k + 2] + wv.w * hl[k + 3];
  }
  A[(size_t)b * HDIM + h] = acc;
}

// ------------- GEMM path 1: pure-DMA m97 structure (both tiles bf16 in ws) -------------
__global__ __launch_bounds__(256) void gemm_pre_kernel(const char* __restrict__ enc16,
                                                       const char* __restrict__ w2s,
                                                       const float* __restrict__ A,
                                                       const float* __restrict__ v,
                                                       float* __restrict__ sp) {
  __shared__ unsigned short As[128][64];  // 16 KB, swizzled image via DMA
  __shared__ unsigned short Bs[128][64];  // 16 KB

  const int lg = (int)((blockIdx.x & 7) * 256 + (blockIdx.x >> 3));
  const int nblk = lg & 7;
  const int mstrip = lg >> 3;
  const int m0 = mstrip * 128;
  const int n0 = nblk * 128;
  const int b = m0 >> 9;

  const int tid = threadIdx.x;
  const int w = tid >> 6, l = tid & 63;
  const int wm = w >> 1, wn = w & 1;
  const int lr = l & 15, lk = l >> 4;

  char* AsB = reinterpret_cast<char*>(&As[0][0]);
  char* BsB = reinterpret_cast<char*>(&Bs[0][0]);

  f32x4 zero = {0.f, 0.f, 0.f, 0.f};
  f32x4 acc[4][4];
#pragma unroll
  for (int fm = 0; fm < 4; ++fm)
#pragma unroll
    for (int fn = 0; fn < 4; ++fn) acc[fm][fn] = zero;

  const char* atile_base = enc16 + (size_t)(mstrip * 16) * 16384;
  const char* btile_base = w2s + (size_t)(nblk * 16) * 16384;

  for (int kt = 0; kt < 16; ++kt) {
    __syncthreads();  // previous step's ds_reads complete
    const char* at = atile_base + (size_t)kt * 16384;
    const char* bt = btile_base + (size_t)kt * 16384;
#pragma unroll
    for (int c = 0; c < 4; ++c) {
      const int off = c * 4096 + w * 1024;
      gld_lds16(at + off + l * 16, AsB + off);
      gld_lds16(bt + off + l * 16, BsB + off);
    }
    __syncthreads();  // vmcnt(0) drain: tiles resident

#pragma unroll
    for (int ks = 0; ks < 2; ++ks) {
      short8 af[4], bfr[4];
#pragma unroll
      for (int f = 0; f < 4; ++f) {
        const int ra = wm * 64 + f * 16 + lr;
        const int ga = (ks * 4 + lk) ^ (ra & 7);
        af[f] = *reinterpret_cast<const short8*>(AsB + ra * 128 + ga * 16);
        const int rb = wn * 64 + f * 16 + lr;
        const int gb = (ks * 4 + lk) ^ (rb & 7);
        bfr[f] = *reinterpret_cast<const short8*>(BsB + rb * 128 + gb * 16);
      }
#pragma unroll
      for (int fm = 0; fm < 4; ++fm)
#pragma unroll
        for (int fn = 0; fn < 4; ++fn)
          acc[fm][fn] = __builtin_amdgcn_mfma_f32_16x16x32_bf16(af[fm], bfr[fn], acc[fm][fn], 0, 0, 0);
    }
  }

  // Epilogue: tanh(C + A) . v, per-row reduce, write partial.
  const float* Ab = A + (size_t)b * HDIM + n0;
  const float* vb = v + n0;
  float a_n[4], v_n[4];
#pragma unroll
  for (int fn = 0; fn < 4; ++fn) {
    const int n = wn * 64 + fn * 16 + lr;
    a_n[fn] = Ab[n];
    v_n[fn] = vb[n];
  }
  float part[4][4];
#pragma unroll
  for (int fm = 0; fm < 4; ++fm) {
#pragma unroll
    for (int r = 0; r < 4; ++r) {
      float s = 0.f;
#pragma unroll
      for (int fn = 0; fn < 4; ++fn)
        s += v_n[fn] * tanhf(acc[fm][fn][r] + a_n[fn]);
      s += __shfl_xor(s, 1);
      s += __shfl_xor(s, 2);
      s += __shfl_xor(s, 4);
      s += __shfl_xor(s, 8);
      part[fm][r] = s;
    }
  }
  __syncthreads();
  float* red = reinterpret_cast<float*>(&As[0][0]);
  if (wn == 0 && lr == 0) {
#pragma unroll
    for (int fm = 0; fm < 4; ++fm)
#pragma unroll
      for (int r = 0; r < 4; ++r)
        red[wm * 64 + fm * 16 + lk * 4 + r] = part[fm][r];
  }
  __syncthreads();
  if (wn == 1 && lr == 0) {
#pragma unroll
    for (int fm = 0; fm < 4; ++fm)
#pragma unroll
      for (int r = 0; r < 4; ++r)
        red[wm * 64 + fm * 16 + lk * 4 + r] += part[fm][r];
  }
  __syncthreads();
  if (tid < 128) sp[(size_t)nblk * MTOT + m0 + tid] = red[tid];
}

// ------------- GEMM path 2 (fallback, r2 version: inline convert) -------------
__global__ __launch_bounds__(256) void gemm_cvt_kernel(const float* __restrict__ enc,
                                                       const char* __restrict__ w2s,
                                                       const float* __restrict__ A,
                                                       const float* __restrict__ v,
                                                       float* __restrict__ sp) {
  __shared__ unsigned short As[128][64];
  __shared__ unsigned short Bs[128][64];

  const int lg = (int)((blockIdx.x & 7) * 256 + (blockIdx.x >> 3));
  const int nblk = lg & 7;
  const int mstrip = lg >> 3;
  const int m0 = mstrip * 128;
  const int n0 = nblk * 128;
  const int b = m0 >> 9;

  const int tid = threadIdx.x;
  const int w = tid >> 6, l = tid & 63;
  const int wm = w >> 1, wn = w & 1;
  const int lr = l & 15, lk = l >> 4;

  char* AsB = reinterpret_cast<char*>(&As[0][0]);
  char* BsB = reinterpret_cast<char*>(&Bs[0][0]);

  f32x4 zero = {0.f, 0.f, 0.f, 0.f};
  f32x4 acc[4][4];
#pragma unroll
  for (int fm = 0; fm < 4; ++fm)
#pragma unroll
    for (int fn = 0; fn < 4; ++fn) acc[fm][fn] = zero;

  const char* wtile_base = w2s + ((size_t)nblk * 16) * 16384;

  for (int kt = 0; kt < 16; ++kt) {
    const int kk = kt * 64;
    __syncthreads();
    const float* encb = enc + (size_t)m0 * HDIM + kk;
#pragma unroll
    for (int i = 0; i < 4; ++i) {
      const int j = tid + i * 256;
      const int row = j >> 3, g = j & 7;
      const float* src = encb + (size_t)row * HDIM + g * 8;
      const float4 f0 = *reinterpret_cast<const float4*>(src);
      const float4 f1 = *reinterpret_cast<const float4*>(src + 4);
      uint4 u = make_uint4(cvt2(f0.x, f0.y), cvt2(f0.z, f0.w),
                           cvt2(f1.x, f1.y), cvt2(f1.z, f1.w));
      *reinterpret_cast<uint4*>(AsB + row * 128 + (g ^ (row & 7)) * 16) = u;
    }
    const char* wtile = wtile_base + (size_t)kt * 16384;
#pragma unroll
    for (int c = 0; c < 4; ++c) {
      const int off = c * 4096 + w * 1024;
      gld_lds16(wtile + off + l * 16, BsB + off);
    }
    __syncthreads();

#pragma unroll
    for (int ks = 0; ks < 2; ++ks) {
      short8 af[4], bfr[4];
#pragma unroll
      for (int f = 0; f < 4; ++f) {
        const int ra = wm * 64 + f * 16 + lr;
        const int ga = (ks * 4 + lk) ^ (ra & 7);
        af[f] = *reinterpret_cast<const short8*>(AsB + ra * 128 + ga * 16);
        const int rb = wn * 64 + f * 16 + lr;
        const int gb = (ks * 4 + lk) ^ (rb & 7);
        bfr[f] = *reinterpret_cast<const short8*>(BsB + rb * 128 + gb * 16);
      }
#pragma unroll
      for (int fm = 0; fm < 4; ++fm)
#pragma unroll
        for (int fn = 0; fn < 4; ++fn)
          acc[fm][fn] = __builtin_amdgcn_mfma_f32_16x16x32_bf16(af[fm], bfr[fn], acc[fm][fn], 0, 0, 0);
    }
  }

  const float* Ab = A + (size_t)b * HDIM + n0;
  const float* vb = v + n0;
  float a_n[4], v_n[4];
#pragma unroll
  for (int fn = 0; fn < 4; ++fn) {
    const int n = wn * 64 + fn * 16 + lr;
    a_n[fn] = Ab[n];
    v_n[fn] = vb[n];
  }
  float part[4][4];
#pragma unroll
  for (int fm = 0; fm < 4; ++fm) {
#pragma unroll
    for (int r = 0; r < 4; ++r) {
      float s = 0.f;
#pragma unroll
      for (int fn = 0; fn < 4; ++fn)
        s += v_n[fn] * tanhf(acc[fm][fn][r] + a_n[fn]);
      s += __shfl_xor(s, 1);
      s += __shfl_xor(s, 2);
      s += __shfl_xor(s, 4);
      s += __shfl_xor(s, 8);
      part[fm][r] = s;
    }
  }
  __syncthreads();
  float* red = reinterpret_cast<float*>(&As[0][0]);
  if (wn == 0 && lr == 0) {
#pragma unroll
    for (int fm = 0; fm < 4; ++fm)
#pragma unroll
      for (int r = 0; r < 4; ++r)
        red[wm * 64 + fm * 16 + lk * 4 + r] = part[fm][r];
  }
  __syncthreads();
  if (wn == 1 && lr == 0) {
#pragma unroll
    for (int fm = 0; fm < 4; ++fm)
#pragma unroll
      for (int r = 0; r < 4; ++r)
        red[wm * 64 + fm * 16 + lk * 4 + r] += part[fm][r];
  }
  __syncthreads();
  if (tid < 128) sp[(size_t)nblk * MTOT + m0 + tid] = red[tid];
}

// ---------------- softmax (unchanged) ----------------
__global__ __launch_bounds__(512) void softmax_kernel(const float* __restrict__ sp,
                                                      float* __restrict__ wts) {
  const int b = blockIdx.x, s = threadIdx.x;
  float sc = 0.f;
#pragma unroll
  for (int j = 0; j < 8; ++j) sc += sp[(size_t)j * MTOT + b * SDIM + s];
  float m = sc;
#pragma unroll
  for (int d = 1; d < 64; d <<= 1) m = fmaxf(m, __shfl_xor(m, d));
  __shared__ float redm[8], reds[8];
  if ((s & 63) == 0) redm[s >> 6] = m;
  __syncthreads();
  m = redm[0];
#pragma unroll
  for (int j = 1; j < 8; ++j) m = fmaxf(m, redm[j]);
  const float e = expf(sc - m);
  float sum = e;
#pragma unroll
  for (int d = 1; d < 64; d <<= 1) sum += __shfl_xor(sum, d);
  if ((s & 63) == 0) reds[s >> 6] = sum;
  __syncthreads();
  float tot = 0.f;
#pragma unroll
  for (int j = 0; j < 8; ++j) tot += reds[j];
  wts[(size_t)b * SDIM + s] = e / tot;
}

// ---------------- context (unchanged) ----------------
__global__ __launch_bounds__(256) void context_kernel(const float* __restrict__ enc,
                                                      const float* __restrict__ wts,
                                                      float* __restrict__ ctx) {
  const int hc = blockIdx.x;
  const int b  = blockIdx.y;
  const int t  = threadIdx.x;
  __shared__ float wl[SDIM];
  wl[t] = wts[(size_t)b * SDIM + t];
  wl[t + 256] = wts[(size_t)b * SDIM + 256 + t];
  __syncthreads();
  const int h = hc * 256 + t;
  const float* e0 = enc + (size_t)b * SDIM * HDIM + h;
  float acc0 = 0.f, acc1 = 0.f;
  for (int s = 0; s < SDIM; s += 2) {
    acc0 += wl[s] * e0[(size_t)s * HDIM];
    acc1 += wl[s + 1] * e0[(size_t)(s + 1) * HDIM];
  }
  ctx[(size_t)b * HDIM + h] = acc0 + acc1;
}

extern "C" void kernel_launch(void* const* d_in, const int* in_sizes, int n_in,
                              void* d_out, int out_size, void* d_ws, size_t ws_size,
                              hipStream_t stream) {
  const float* hidden = (const float*)d_in[0];
  const float* enc    = (const float*)d_in[1];
  const float* W      = (const float*)d_in[2];
  const float* bias   = (const float*)d_in[3];
  const float* v      = (const float*)d_in[4];

  float* ctx = (float*)d_out;
  float* wts = (float*)d_out + BDIM * HDIM;

  char* ws = (char*)d_ws;
  const size_t ENC16_BYTES = (size_t)64 * 1024 * 1024;  // 32768 x 1024 bf16
  const size_t BIG_NEED = ENC16_BYTES + 2 * 1024 * 1024 + 256 * 1024 + 1024 * 1024;

  if (ws_size >= BIG_NEED) {
    char* enc16 = ws;
    char* w2s   = ws + ENC16_BYTES;
    float* A    = (float*)(ws + ENC16_BYTES + 2 * 1024 * 1024);
    float* sp   = (float*)(ws + ENC16_BYTES + 2 * 1024 * 1024 + 256 * 1024);
    hipLaunchKernelGGL(prep_w2_kernel, dim3(512), dim3(256), 0, stream, W, w2s);
    hipLaunchKernelGGL(prep_enc_kernel, dim3(16, 256), dim3(256), 0, stream, enc, enc16);
    hipLaunchKernelGGL(compute_a_kernel, dim3(4, 64), dim3(256), 0, stream, hidden, W, bias, A);
    hipLaunchKernelGGL(gemm_pre_kernel, dim3(2048), dim3(256), 0, stream, enc16, w2s, A, v, sp);
    hipLaunchKernelGGL(softmax_kernel, dim3(64), dim3(512), 0, stream, sp, wts);
    hipLaunchKernelGGL(context_kernel, dim3(4, 64), dim3(256), 0, stream, enc, wts, ctx);
  } else {
    char* w2s = ws;
    float* A  = (float*)(ws + (size_t)2 * 1024 * 1024);
    float* sp = (float*)(ws + (size_t)2 * 1024 * 1024 + 256 * 1024);
    hipLaunchKernelGGL(prep_w2_kernel, dim3(512), dim3(256), 0, stream, W, w2s);
    hipLaunchKernelGGL(compute_a_kernel, dim3(4, 64), dim3(256), 0, stream, hidden, W, bias, A);
    hipLaunchKernelGGL(gemm_cvt_kernel, dim3(2048), dim3(256), 0, stream, enc, w2s, A, v, sp);
    hipLaunchKernelGGL(softmax_kernel, dim3(64), dim3(512), 0, stream, sp, wts);
    hipLaunchKernelGGL(context_kernel, dim3(4, 64), dim3(256), 0, stream, enc, wts, ctx);
  }
}

// Round 5
// 195.502 us; speedup vs baseline: 1.0110x; 1.0093x over previous
//
#include <hip/hip_runtime.h>
#include <hip/hip_bf16.h>
#include <cstdint>
#include <cstddef>

#define BDIM 64
#define SDIM 512
#define HDIM 1024
#define MTOT (BDIM * SDIM)  // 32768

typedef __attribute__((ext_vector_type(8))) short short8;
typedef __attribute__((ext_vector_type(4))) float f32x4;

__device__ __forceinline__ unsigned int cvt2(float a, float b) {
  unsigned int r;
  asm("v_cvt_pk_bf16_f32 %0, %1, %2" : "=v"(r) : "v"(a), "v"(b));
  return r;
}

__device__ __forceinline__ void gld_lds16(const void* g, void* l) {
  __builtin_amdgcn_global_load_lds(
      (const __attribute__((address_space(1))) unsigned int*)g,
      (__attribute__((address_space(3))) unsigned int*)l, 16, 0, 0);
}

// tanh via hw exp2 + rcp: tanh(x) = 1 - 2/(e^{2x}+1). |err| ~1e-6, correct sat.
__device__ __forceinline__ float fast_tanh(float x) {
  const float e = __builtin_exp2f(x * 2.88539008f);  // 2*log2(e)
  return 1.0f - 2.0f * __builtin_amdgcn_rcpf(e + 1.0f);
}

// ---- fused prep: [0,4096) enc->bf16 swizzled tiles | [4096,4608) W2 tiles |
//      [4608,4864) A = hidden.W1 + bias ----
__global__ __launch_bounds__(256) void fused_prep_kernel(const float* __restrict__ enc,
                                                         const float* __restrict__ W,
                                                         const float* __restrict__ hidden,
                                                         const float* __restrict__ bias,
                                                         char* __restrict__ enc16,
                                                         char* __restrict__ w2s,
                                                         float* __restrict__ A) {
  __shared__ float hl[HDIM];
  const int bid = blockIdx.x;
  const int tid = threadIdx.x;
  if (bid < 4096) {
    const int kt = bid & 15, mstrip = bid >> 4;
    const float* src0 = enc + (size_t)mstrip * 128 * HDIM + kt * 64;
    char* tile = enc16 + (size_t)(mstrip * 16 + kt) * 16384;
#pragma unroll
    for (int i = 0; i < 4; ++i) {
      const int j = tid + i * 256;
      const int row = j >> 3, g = j & 7;
      const float* s = src0 + (size_t)row * HDIM + g * 8;
      const float4 f0 = *reinterpret_cast<const float4*>(s);
      const float4 f1 = *reinterpret_cast<const float4*>(s + 4);
      uint4 u = make_uint4(cvt2(f0.x, f0.y), cvt2(f0.z, f0.w),
                           cvt2(f1.x, f1.y), cvt2(f1.z, f1.w));
      *reinterpret_cast<uint4*>(tile + row * 128 + (g ^ (row & 7)) * 16) = u;
    }
  } else if (bid < 4608) {
    const int bx = bid - 4096;
    const int n = bx * 2 + (tid >> 7);
    const int g = tid & 127;
    const int kt = g >> 3, gi = g & 7;
    const float* src = W + (size_t)n * 2048 + 1024 + g * 8;
    const float4 f0 = *reinterpret_cast<const float4*>(src);
    const float4 f1 = *reinterpret_cast<const float4*>(src + 4);
    uint4 u = make_uint4(cvt2(f0.x, f0.y), cvt2(f0.z, f0.w),
                         cvt2(f1.x, f1.y), cvt2(f1.z, f1.w));
    const int nblk = n >> 7, row = n & 127;
    const size_t off = ((size_t)(nblk * 16 + kt) * 128 + row) * 128 +
                       (size_t)(gi ^ (row & 7)) * 16;
    *reinterpret_cast<uint4*>(w2s + off) = u;
  } else {
    const int bx = bid - 4608;
    const int hc = bx & 3, b = bx >> 2;
    *reinterpret_cast<float4*>(&hl[tid * 4]) =
        *reinterpret_cast<const float4*>(hidden + (size_t)b * HDIM + tid * 4);
    __syncthreads();
    const int h = hc * 256 + tid;
    const float* wr = W + (size_t)h * 2048;
    float acc = bias[h];
    for (int k = 0; k < HDIM; k += 4) {
      const float4 wv = *reinterpret_cast<const float4*>(wr + k);
      acc += wv.x * hl[k] + wv.y * hl[k + 1] + wv.z * hl[k + 2] + wv.w * hl[k + 3];
    }
    A[(size_t)b * HDIM + h] = acc;
  }
}

// ---- main GEMM: 256x256 tile, 8 waves (2m x 4n), BK=64, dbuf, 4 MFMA phases/K-tile ----
__global__ __launch_bounds__(512, 2) void gemm8_kernel(const char* __restrict__ enc16,
                                                       const char* __restrict__ w2s,
                                                       const float* __restrict__ A,
                                                       const float* __restrict__ v,
                                                       float* __restrict__ sp) {
  __shared__ __align__(16) unsigned short As[2][2][128][64];  // [dbuf][half][row][k] 64KB
  __shared__ __align__(16) unsigned short Bs[2][2][128][64];  // 64KB
  __shared__ float red4[4][256];                              // 4KB

  const int bid = blockIdx.x;
  const int lg = (bid & 7) * 64 + (bid >> 3);  // XCD swizzle, 512 % 8 == 0
  const int nblk = lg & 3, mstrip = lg >> 2;
  const int m0 = mstrip * 256, n0 = nblk * 256;
  const int b = m0 >> 9;  // 256-row strip never crosses a b boundary (512%256==0)

  const int tid = threadIdx.x;
  const int w = tid >> 6, l = tid & 63;
  const int wm = w >> 2, wn = w & 3;  // 2 x 4 wave grid
  const int lr = l & 15, lk = l >> 4;

  f32x4 acc[8][4];
#pragma unroll
  for (int i = 0; i < 8; ++i)
#pragma unroll
    for (int j = 0; j < 4; ++j) acc[i][j] = (f32x4){0.f, 0.f, 0.f, 0.f};

  const char* aT0 = enc16 + (size_t)((mstrip * 2 + 0) * 16) * 16384;
  const char* aT1 = enc16 + (size_t)((mstrip * 2 + 1) * 16) * 16384;
  const char* bT0 = w2s + (size_t)((nblk * 2 + 0) * 16) * 16384;
  const char* bT1 = w2s + (size_t)((nblk * 2 + 1) * 16) * 16384;

  const int wbase = w * 1024;  // per-wave uniform LDS chunk
  const int lofs = l * 16;

#define STAGE(srcp, dstp)                                                  \
  do {                                                                     \
    gld_lds16((const char*)(srcp) + wbase + lofs, (char*)(dstp) + wbase);  \
    gld_lds16((const char*)(srcp) + 8192 + wbase + lofs,                   \
              (char*)(dstp) + 8192 + wbase);                               \
  } while (0)

  // prologue: K-tile 0 into buffer 0
  STAGE(aT0, &As[0][0][0][0]);
  STAGE(aT1, &As[0][1][0][0]);
  STAGE(bT0, &Bs[0][0][0][0]);
  STAGE(bT1, &Bs[0][1][0][0]);

  const int gax = lr & 7;  // fragment row & 7 (row = f*16 + lr)

  for (int kt = 0; kt < 16; ++kt) {
    const int cur = kt & 1, nxt = cur ^ 1;
    __syncthreads();  // vmcnt(0)+lgkmcnt(0)+barrier: tile kt fully resident
    const size_t ko = (size_t)(kt + 1) * 16384;
    const bool pf = (kt < 15);
    const char* Ah = (const char*)&As[cur][wm][0][0];
    const char* Bh = (const char*)&Bs[cur][wn >> 1][0][0];
    const int brow0 = (wn & 1) * 64;

    short8 af[4], bf[4];
#pragma unroll
    for (int ks = 0; ks < 2; ++ks) {
      const int gq = ((ks * 4 + lk) ^ gax) * 16;
#pragma unroll
      for (int mg = 0; mg < 2; ++mg) {
        // stage one half-tile of kt+1 per phase (into the other buffer)
        if (pf) {
          const int ph = ks * 2 + mg;
          if (ph == 0)      STAGE(aT0 + ko, &As[nxt][0][0][0]);
          else if (ph == 1) STAGE(bT0 + ko, &Bs[nxt][0][0][0]);
          else if (ph == 2) STAGE(aT1 + ko, &As[nxt][1][0][0]);
          else              STAGE(bT1 + ko, &Bs[nxt][1][0][0]);
        }
        if (mg == 0) {
#pragma unroll
          for (int f = 0; f < 4; ++f)
            bf[f] = *reinterpret_cast<const short8*>(
                Bh + (brow0 + f * 16 + lr) * 128 + gq);
        }
#pragma unroll
        for (int f = 0; f < 4; ++f)
          af[f] = *reinterpret_cast<const short8*>(
              Ah + ((mg * 4 + f) * 16 + lr) * 128 + gq);
        asm volatile("s_waitcnt lgkmcnt(0)" ::: "memory");
        __builtin_amdgcn_sched_barrier(0);
        __builtin_amdgcn_s_setprio(1);
#pragma unroll
        for (int fm = 0; fm < 4; ++fm)
#pragma unroll
          for (int fn = 0; fn < 4; ++fn)
            acc[mg * 4 + fm][fn] = __builtin_amdgcn_mfma_f32_16x16x32_bf16(
                af[fm], bf[fn], acc[mg * 4 + fm][fn], 0, 0, 0);
        __builtin_amdgcn_s_setprio(0);
      }
    }
  }
#undef STAGE

  // ---- epilogue: sp_partial[m] = sum_n v[n] * tanh(C[m,n] + A[b,n]) over this n-range ----
  float a_n[4], v_n[4];
#pragma unroll
  for (int fn = 0; fn < 4; ++fn) {
    const int n = wn * 64 + fn * 16 + lr;
    a_n[fn] = A[(size_t)b * HDIM + n0 + n];
    v_n[fn] = v[n0 + n];
  }
#pragma unroll
  for (int fm8 = 0; fm8 < 8; ++fm8) {
#pragma unroll
    for (int r = 0; r < 4; ++r) {
      float s = 0.f;
#pragma unroll
      for (int fn = 0; fn < 4; ++fn)
        s += v_n[fn] * fast_tanh(acc[fm8][fn][r] + a_n[fn]);
      s += __shfl_xor(s, 1);
      s += __shfl_xor(s, 2);
      s += __shfl_xor(s, 4);
      s += __shfl_xor(s, 8);
      if (lr == 0) red4[wn][wm * 128 + fm8 * 16 + lk * 4 + r] = s;
    }
  }
  __syncthreads();
  if (tid < 256) {
    const float ssum = red4[0][tid] + red4[1][tid] + red4[2][tid] + red4[3][tid];
    sp[(size_t)nblk * MTOT + m0 + tid] = ssum;
  }
}

// ---- softmax over s (512) per b; sums 4 partials ----
__global__ __launch_bounds__(512) void softmax4_kernel(const float* __restrict__ sp,
                                                       float* __restrict__ wts) {
  const int b = blockIdx.x, s = threadIdx.x;
  float sc = 0.f;
#pragma unroll
  for (int j = 0; j < 4; ++j) sc += sp[(size_t)j * MTOT + b * SDIM + s];
  float m = sc;
#pragma unroll
  for (int d = 1; d < 64; d <<= 1) m = fmaxf(m, __shfl_xor(m, d));
  __shared__ float redm[8], reds[8];
  if ((s & 63) == 0) redm[s >> 6] = m;
  __syncthreads();
  m = redm[0];
#pragma unroll
  for (int j = 1; j < 8; ++j) m = fmaxf(m, redm[j]);
  const float e = expf(sc - m);
  float sum = e;
#pragma unroll
  for (int d = 1; d < 64; d <<= 1) sum += __shfl_xor(sum, d);
  if ((s & 63) == 0) reds[s >> 6] = sum;
  __syncthreads();
  float tot = 0.f;
#pragma unroll
  for (int j = 0; j < 8; ++j) tot += reds[j];
  wts[(size_t)b * SDIM + s] = e / tot;
}

// ---- context[b,h] = sum_s w[b,s] * enc[b,s,h] ----
__global__ __launch_bounds__(256) void context_kernel(const float* __restrict__ enc,
                                                      const float* __restrict__ wts,
                                                      float* __restrict__ ctx) {
  const int hc = blockIdx.x;
  const int b  = blockIdx.y;
  const int t  = threadIdx.x;
  __shared__ float wl[SDIM];
  wl[t] = wts[(size_t)b * SDIM + t];
  wl[t + 256] = wts[(size_t)b * SDIM + 256 + t];
  __syncthreads();
  const int h = hc * 256 + t;
  const float* e0 = enc + (size_t)b * SDIM * HDIM + h;
  float acc0 = 0.f, acc1 = 0.f;
  for (int s = 0; s < SDIM; s += 2) {
    acc0 += wl[s] * e0[(size_t)s * HDIM];
    acc1 += wl[s + 1] * e0[(size_t)(s + 1) * HDIM];
  }
  ctx[(size_t)b * HDIM + h] = acc0 + acc1;
}

// ================== fallback path (small ws), r4-proven ==================
__global__ __launch_bounds__(256) void prep_w2_kernel(const float* __restrict__ W,
                                                      char* __restrict__ w2s) {
  const int n = blockIdx.x * 2 + (threadIdx.x >> 7);
  const int g = threadIdx.x & 127;
  const int kt = g >> 3, gi = g & 7;
  const float* src = W + (size_t)n * 2048 + 1024 + g * 8;
  const float4 f0 = *reinterpret_cast<const float4*>(src);
  const float4 f1 = *reinterpret_cast<const float4*>(src + 4);
  uint4 u = make_uint4(cvt2(f0.x, f0.y), cvt2(f0.z, f0.w),
                       cvt2(f1.x, f1.y), cvt2(f1.z, f1.w));
  const int nblk = n >> 7, row = n & 127;
  const size_t off = ((size_t)(nblk * 16 + kt) * 128 + row) * 128 +
                     (size_t)(gi ^ (row & 7)) * 16;
  *reinterpret_cast<uint4*>(w2s + off) = u;
}

__global__ __launch_bounds__(256) void compute_a_kernel(const float* __restrict__ hidden,
                                                        const float* __restrict__ W,
                                                        const float* __restrict__ bias,
                                                        float* __restrict__ A) {
  const int hc = blockIdx.x;
  const int b  = blockIdx.y;
  const int t  = threadIdx.x;
  __shared__ float hl[HDIM];
  *reinterpret_cast<float4*>(&hl[t * 4]) =
      *reinterpret_cast<const float4*>(hidden + (size_t)b * HDIM + t * 4);
  __syncthreads();
  const int h = hc * 256 + t;
  const float* wr = W + (size_t)h * 2048;
  float acc = bias[h];
  for (int k = 0; k < HDIM; k += 4) {
    const float4 wv = *reinterpret_cast<const float4*>(wr + k);
    acc += wv.x * hl[k] + wv.y * hl[k + 1] + wv.z * hl[k + 2] + wv.w * hl[k + 3];
  }
  A[(size_t)b * HDIM + h] = acc;
}

__global__ __launch_bounds__(256) void gemm_cvt_kernel(const float* __restrict__ enc,
                                                       const char* __restrict__ w2s,
                                                       const float* __restrict__ A,
                                                       const float* __restrict__ v,
                                                       float* __restrict__ sp) {
  __shared__ unsigned short As[128][64];
  __shared__ unsigned short Bs[128][64];
  const int lg = (int)((blockIdx.x & 7) * 256 + (blockIdx.x >> 3));
  const int nblk = lg & 7;
  const int mstrip = lg >> 3;
  const int m0 = mstrip * 128;
  const int n0 = nblk * 128;
  const int b = m0 >> 9;
  const int tid = threadIdx.x;
  const int w = tid >> 6, l = tid & 63;
  const int wm = w >> 1, wn = w & 1;
  const int lr = l & 15, lk = l >> 4;
  char* AsB = reinterpret_cast<char*>(&As[0][0]);
  char* BsB = reinterpret_cast<char*>(&Bs[0][0]);
  f32x4 acc[4][4];
#pragma unroll
  for (int fm = 0; fm < 4; ++fm)
#pragma unroll
    for (int fn = 0; fn < 4; ++fn) acc[fm][fn] = (f32x4){0.f, 0.f, 0.f, 0.f};
  const char* wtile_base = w2s + ((size_t)nblk * 16) * 16384;
  for (int kt = 0; kt < 16; ++kt) {
    const int kk = kt * 64;
    __syncthreads();
    const float* encb = enc + (size_t)m0 * HDIM + kk;
#pragma unroll
    for (int i = 0; i < 4; ++i) {
      const int j = tid + i * 256;
      const int row = j >> 3, g = j & 7;
      const float* src = encb + (size_t)row * HDIM + g * 8;
      const float4 f0 = *reinterpret_cast<const float4*>(src);
      const float4 f1 = *reinterpret_cast<const float4*>(src + 4);
      uint4 u = make_uint4(cvt2(f0.x, f0.y), cvt2(f0.z, f0.w),
                           cvt2(f1.x, f1.y), cvt2(f1.z, f1.w));
      *reinterpret_cast<uint4*>(AsB + row * 128 + (g ^ (row & 7)) * 16) = u;
    }
    const char* wtile = wtile_base + (size_t)kt * 16384;
#pragma unroll
    for (int c = 0; c < 4; ++c) {
      const int off = c * 4096 + w * 1024;
      gld_lds16(wtile + off + l * 16, BsB + off);
    }
    __syncthreads();
#pragma unroll
    for (int ks = 0; ks < 2; ++ks) {
      short8 af[4], bfr[4];
#pragma unroll
      for (int f = 0; f < 4; ++f) {
        const int ra = wm * 64 + f * 16 + lr;
        const int ga = (ks * 4 + lk) ^ (ra & 7);
        af[f] = *reinterpret_cast<const short8*>(AsB + ra * 128 + ga * 16);
        const int rb = wn * 64 + f * 16 + lr;
        const int gb = (ks * 4 + lk) ^ (rb & 7);
        bfr[f] = *reinterpret_cast<const short8*>(BsB + rb * 128 + gb * 16);
      }
#pragma unroll
      for (int fm = 0; fm < 4; ++fm)
#pragma unroll
        for (int fn = 0; fn < 4; ++fn)
          acc[fm][fn] = __builtin_amdgcn_mfma_f32_16x16x32_bf16(af[fm], bfr[fn], acc[fm][fn], 0, 0, 0);
    }
  }
  const float* Ab = A + (size_t)b * HDIM + n0;
  const float* vb = v + n0;
  float a_n[4], v_n[4];
#pragma unroll
  for (int fn = 0; fn < 4; ++fn) {
    const int n = wn * 64 + fn * 16 + lr;
    a_n[fn] = Ab[n];
    v_n[fn] = vb[n];
  }
  float part[4][4];
#pragma unroll
  for (int fm = 0; fm < 4; ++fm) {
#pragma unroll
    for (int r = 0; r < 4; ++r) {
      float s = 0.f;
#pragma unroll
      for (int fn = 0; fn < 4; ++fn)
        s += v_n[fn] * fast_tanh(acc[fm][fn][r] + a_n[fn]);
      s += __shfl_xor(s, 1);
      s += __shfl_xor(s, 2);
      s += __shfl_xor(s, 4);
      s += __shfl_xor(s, 8);
      part[fm][r] = s;
    }
  }
  __syncthreads();
  float* red = reinterpret_cast<float*>(&As[0][0]);
  if (wn == 0 && lr == 0) {
#pragma unroll
    for (int fm = 0; fm < 4; ++fm)
#pragma unroll
      for (int r = 0; r < 4; ++r)
        red[wm * 64 + fm * 16 + lk * 4 + r] = part[fm][r];
  }
  __syncthreads();
  if (wn == 1 && lr == 0) {
#pragma unroll
    for (int fm = 0; fm < 4; ++fm)
#pragma unroll
      for (int r = 0; r < 4; ++r)
        red[wm * 64 + fm * 16 + lk * 4 + r] += part[fm][r];
  }
  __syncthreads();
  if (tid < 128) sp[(size_t)nblk * MTOT + m0 + tid] = red[tid];
}

__global__ __launch_bounds__(512) void softmax8_kernel(const float* __restrict__ sp,
                                                       float* __restrict__ wts) {
  const int b = blockIdx.x, s = threadIdx.x;
  float sc = 0.f;
#pragma unroll
  for (int j = 0; j < 8; ++j) sc += sp[(size_t)j * MTOT + b * SDIM + s];
  float m = sc;
#pragma unroll
  for (int d = 1; d < 64; d <<= 1) m = fmaxf(m, __shfl_xor(m, d));
  __shared__ float redm[8], reds[8];
  if ((s & 63) == 0) redm[s >> 6] = m;
  __syncthreads();
  m = redm[0];
#pragma unroll
  for (int j = 1; j < 8; ++j) m = fmaxf(m, redm[j]);
  const float e = expf(sc - m);
  float sum = e;
#pragma unroll
  for (int d = 1; d < 64; d <<= 1) sum += __shfl_xor(sum, d);
  if ((s & 63) == 0) reds[s >> 6] = sum;
  __syncthreads();
  float tot = 0.f;
#pragma unroll
  for (int j = 0; j < 8; ++j) tot += reds[j];
  wts[(size_t)b * SDIM + s] = e / tot;
}

extern "C" void kernel_launch(void* const* d_in, const int* in_sizes, int n_in,
                              void* d_out, int out_size, void* d_ws, size_t ws_size,
                              hipStream_t stream) {
  const float* hidden = (const float*)d_in[0];
  const float* enc    = (const float*)d_in[1];
  const float* W      = (const float*)d_in[2];
  const float* bias   = (const float*)d_in[3];
  const float* v      = (const float*)d_in[4];

  float* ctx = (float*)d_out;
  float* wts = (float*)d_out + BDIM * HDIM;

  char* ws = (char*)d_ws;
  const size_t ENC16_BYTES = (size_t)64 * 1024 * 1024;
  const size_t BIG_NEED = ENC16_BYTES + 2 * 1024 * 1024 + 256 * 1024 + 1024 * 1024;

  if (ws_size >= BIG_NEED) {
    char* enc16 = ws;
    char* w2s   = ws + ENC16_BYTES;
    float* A    = (float*)(ws + ENC16_BYTES + 2 * 1024 * 1024);
    float* sp   = (float*)(ws + ENC16_BYTES + 2 * 1024 * 1024 + 256 * 1024);
    hipLaunchKernelGGL(fused_prep_kernel, dim3(4864), dim3(256), 0, stream,
                       enc, W, hidden, bias, enc16, w2s, A);
    hipLaunchKernelGGL(gemm8_kernel, dim3(512), dim3(512), 0, stream, enc16, w2s, A, v, sp);
    hipLaunchKernelGGL(softmax4_kernel, dim3(64), dim3(512), 0, stream, sp, wts);
    hipLaunchKernelGGL(context_kernel, dim3(4, 64), dim3(256), 0, stream, enc, wts, ctx);
  } else {
    char* w2s = ws;
    float* A  = (float*)(ws + (size_t)2 * 1024 * 1024);
    float* sp = (float*)(ws + (size_t)2 * 1024 * 1024 + 256 * 1024);
    hipLaunchKernelGGL(prep_w2_kernel, dim3(512), dim3(256), 0, stream, W, w2s);
    hipLaunchKernelGGL(compute_a_kernel, dim3(4, 64), dim3(256), 0, stream, hidden, W, bias, A);
    hipLaunchKernelGGL(gemm_cvt_kernel, dim3(2048), dim3(256), 0, stream, enc, w2s, A, v, sp);
    hipLaunchKernelGGL(softmax8_kernel, dim3(64), dim3(512), 0, stream, sp, wts);
    hipLaunchKernelGGL(context_kernel, dim3(4, 64), dim3(256), 0, stream, enc, wts, ctx);
  }
}

// Round 6
// 143.634 us; speedup vs baseline: 1.3761x; 1.3611x over previous
//
#include <hip/hip_runtime.h>
#include <hip/hip_bf16.h>
#include <cstdint>
#include <cstddef>

#define BDIM 64
#define SDIM 512
#define HDIM 1024
#define MTOT (BDIM * SDIM)  // 32768

typedef __attribute__((ext_vector_type(8))) short short8;
typedef __attribute__((ext_vector_type(4))) float f32x4;

__device__ __forceinline__ unsigned int cvt2(float a, float b) {
  unsigned int r;
  asm("v_cvt_pk_bf16_f32 %0, %1, %2" : "=v"(r) : "v"(a), "v"(b));
  return r;
}

__device__ __forceinline__ void gld_lds16(const void* g, void* l) {
  __builtin_amdgcn_global_load_lds(
      (const __attribute__((address_space(1))) unsigned int*)g,
      (__attribute__((address_space(3))) unsigned int*)l, 16, 0, 0);
}

// tanh via hw exp2 + rcp: tanh(x) = 1 - 2/(e^{2x}+1). |err| ~1e-6, correct sat.
__device__ __forceinline__ float fast_tanh(float x) {
  const float e = __builtin_exp2f(x * 2.88539008f);  // 2*log2(e)
  return 1.0f - 2.0f * __builtin_amdgcn_rcpf(e + 1.0f);
}

// ---- W2 -> bf16, tile-major + XOR-swizzled (proven r2-r5) ----
__global__ __launch_bounds__(256) void prep_w2_kernel(const float* __restrict__ W,
                                                      char* __restrict__ w2s) {
  const int n = blockIdx.x * 2 + (threadIdx.x >> 7);
  const int g = threadIdx.x & 127;
  const int kt = g >> 3, gi = g & 7;
  const float* src = W + (size_t)n * 2048 + 1024 + g * 8;
  const float4 f0 = *reinterpret_cast<const float4*>(src);
  const float4 f1 = *reinterpret_cast<const float4*>(src + 4);
  uint4 u = make_uint4(cvt2(f0.x, f0.y), cvt2(f0.z, f0.w),
                       cvt2(f1.x, f1.y), cvt2(f1.z, f1.w));
  const int nblk = n >> 7, row = n & 127;
  const size_t off = ((size_t)(nblk * 16 + kt) * 128 + row) * 128 +
                     (size_t)(gi ^ (row & 7)) * 16;
  *reinterpret_cast<uint4*>(w2s + off) = u;
}

// ---- A[b,h] = hidden.W1 + bias; 4 independent FMA chains ----
__global__ __launch_bounds__(256) void compute_a_kernel(const float* __restrict__ hidden,
                                                        const float* __restrict__ W,
                                                        const float* __restrict__ bias,
                                                        float* __restrict__ A) {
  const int hc = blockIdx.x;  // 0..3
  const int b  = blockIdx.y;  // 0..63
  const int t  = threadIdx.x;
  __shared__ float hl[HDIM];
  *reinterpret_cast<float4*>(&hl[t * 4]) =
      *reinterpret_cast<const float4*>(hidden + (size_t)b * HDIM + t * 4);
  __syncthreads();
  const int h = hc * 256 + t;
  const float* wr = W + (size_t)h * 2048;
  float a0 = 0.f, a1 = 0.f, a2 = 0.f, a3 = 0.f;
  for (int k = 0; k < HDIM; k += 16) {
    const float4 w0 = *reinterpret_cast<const float4*>(wr + k);
    const float4 w1 = *reinterpret_cast<const float4*>(wr + k + 4);
    const float4 w2 = *reinterpret_cast<const float4*>(wr + k + 8);
    const float4 w3 = *reinterpret_cast<const float4*>(wr + k + 12);
    a0 += w0.x * hl[k]      + w0.y * hl[k + 1]  + w0.z * hl[k + 2]  + w0.w * hl[k + 3];
    a1 += w1.x * hl[k + 4]  + w1.y * hl[k + 5]  + w1.z * hl[k + 6]  + w1.w * hl[k + 7];
    a2 += w2.x * hl[k + 8]  + w2.y * hl[k + 9]  + w2.z * hl[k + 10] + w2.w * hl[k + 11];
    a3 += w3.x * hl[k + 12] + w3.y * hl[k + 13] + w3.z * hl[k + 14] + w3.w * hl[k + 15];
  }
  A[(size_t)b * HDIM + h] = bias[h] + ((a0 + a1) + (a2 + a3));
}

// ---- main GEMM, conversion fused: 256x256 tile, 8 waves, BK=64, dbuf,
//      4 MFMA phases/K-tile; A reg-staged f32->bf16, B via global_load_lds ----
__global__ __launch_bounds__(512, 2) void gemm8f_kernel(const float* __restrict__ enc,
                                                        const char* __restrict__ w2s,
                                                        const float* __restrict__ A,
                                                        const float* __restrict__ v,
                                                        float* __restrict__ sp) {
  __shared__ __align__(16) unsigned short As[2][2][128][64];  // 64 KB
  __shared__ __align__(16) unsigned short Bs[2][2][128][64];  // 64 KB
  __shared__ float red4[4][256];                              // 4 KB

  const int bid = blockIdx.x;
  const int lg = (bid & 7) * 64 + (bid >> 3);  // XCD swizzle, 512 % 8 == 0
  const int nblk = lg & 3, mstrip = lg >> 2;
  const int m0 = mstrip * 256, n0 = nblk * 256;
  const int b = m0 >> 9;

  const int tid = threadIdx.x;
  const int w = tid >> 6, l = tid & 63;
  const int wm = w >> 2, wn = w & 3;  // 2 x 4 wave grid
  const int lr = l & 15, lk = l >> 4;

  f32x4 acc[8][4];
#pragma unroll
  for (int i = 0; i < 8; ++i)
#pragma unroll
    for (int j = 0; j < 4; ++j) acc[i][j] = (f32x4){0.f, 0.f, 0.f, 0.f};

  // A staging geometry: thread -> (row0 + i*64, granule g0); 4 iters = 256 rows
  const int row0 = tid >> 3, g0 = tid & 7;
  const float* encA = enc + (size_t)m0 * HDIM + g0 * 8;

  const char* bT0 = w2s + (size_t)((nblk * 2 + 0) * 16) * 16384;
  const char* bT1 = w2s + (size_t)((nblk * 2 + 1) * 16) * 16384;

  const int wbase = w * 1024;
  const int lofs = l * 16;

#define STAGE_B(srcp, dstp)                                                \
  do {                                                                     \
    gld_lds16((const char*)(srcp) + wbase + lofs, (char*)(dstp) + wbase);  \
    gld_lds16((const char*)(srcp) + 8192 + wbase + lofs,                   \
              (char*)(dstp) + 8192 + wbase);                               \
  } while (0)

#define LOAD_A(pfv, ii, ktv)                                               \
  do {                                                                     \
    const float* s_ = encA + (size_t)(row0 + (ii) * 64) * HDIM + (ktv) * 64; \
    pfv[2 * (ii)]     = *reinterpret_cast<const float4*>(s_);              \
    pfv[2 * (ii) + 1] = *reinterpret_cast<const float4*>(s_ + 4);          \
  } while (0)

  float4 pf[8];

  // prologue: A(0) f32 loads into regs; B(0) DMA into buffer 0
  LOAD_A(pf, 0, 0); LOAD_A(pf, 1, 0); LOAD_A(pf, 2, 0); LOAD_A(pf, 3, 0);
  STAGE_B(bT0, &Bs[0][0][0][0]);
  STAGE_B(bT1, &Bs[0][1][0][0]);

  const int gax = lr & 7;

  for (int kt = 0; kt < 16; ++kt) {
    const int cur = kt & 1, nxt = cur ^ 1;
    // (a) convert + write A(kt) into As[cur] (swizzled slots, conflict-free)
#pragma unroll
    for (int i = 0; i < 4; ++i) {
      const int row = row0 + i * 64;
      uint4 u = make_uint4(cvt2(pf[2 * i].x, pf[2 * i].y),
                           cvt2(pf[2 * i].z, pf[2 * i].w),
                           cvt2(pf[2 * i + 1].x, pf[2 * i + 1].y),
                           cvt2(pf[2 * i + 1].z, pf[2 * i + 1].w));
      char* dst = reinterpret_cast<char*>(&As[cur][row >> 7][0][0]);
      *reinterpret_cast<uint4*>(dst + (row & 127) * 128 + ((g0 ^ (row & 7)) * 16)) = u;
    }
    __syncthreads();  // ds_writes visible + B(kt) DMA drained (implicit vmcnt/lgkm 0)

    const bool pfb = (kt < 15);
    const char* Ah = (const char*)&As[cur][wm][0][0];
    const char* Bh = (const char*)&Bs[cur][wn >> 1][0][0];
    const int brow0 = (wn & 1) * 64;

    short8 af[4], bf[4];
#pragma unroll
    for (int ks = 0; ks < 2; ++ks) {
      const int gq = ((ks * 4 + lk) ^ gax) * 16;
#pragma unroll
      for (int mg = 0; mg < 2; ++mg) {
        // issue one prefetch chunk of kt+1 per phase
        if (pfb) {
          const int ph = ks * 2 + mg;
          if (ph == 0)      { LOAD_A(pf, 0, kt + 1); LOAD_A(pf, 1, kt + 1); }
          else if (ph == 1) { LOAD_A(pf, 2, kt + 1); LOAD_A(pf, 3, kt + 1); }
          else if (ph == 2) { STAGE_B(bT0 + (size_t)(kt + 1) * 16384, &Bs[nxt][0][0][0]); }
          else              { STAGE_B(bT1 + (size_t)(kt + 1) * 16384, &Bs[nxt][1][0][0]); }
        }
        if (mg == 0) {
#pragma unroll
          for (int f = 0; f < 4; ++f)
            bf[f] = *reinterpret_cast<const short8*>(
                Bh + (brow0 + f * 16 + lr) * 128 + gq);
        }
#pragma unroll
        for (int f = 0; f < 4; ++f)
          af[f] = *reinterpret_cast<const short8*>(
              Ah + ((mg * 4 + f) * 16 + lr) * 128 + gq);
        asm volatile("s_waitcnt lgkmcnt(0)" ::: "memory");
        __builtin_amdgcn_sched_barrier(0);
        __builtin_amdgcn_s_setprio(1);
#pragma unroll
        for (int fm = 0; fm < 4; ++fm)
#pragma unroll
          for (int fn = 0; fn < 4; ++fn)
            acc[mg * 4 + fm][fn] = __builtin_amdgcn_mfma_f32_16x16x32_bf16(
                af[fm], bf[fn], acc[mg * 4 + fm][fn], 0, 0, 0);
        __builtin_amdgcn_s_setprio(0);
      }
    }
  }
#undef STAGE_B
#undef LOAD_A

  // ---- epilogue: partial[m] = sum_n v[n] * tanh(C[m,n] + A[b,n]) ----
  float a_n[4], v_n[4];
#pragma unroll
  for (int fn = 0; fn < 4; ++fn) {
    const int n = wn * 64 + fn * 16 + lr;
    a_n[fn] = A[(size_t)b * HDIM + n0 + n];
    v_n[fn] = v[n0 + n];
  }
#pragma unroll
  for (int fm8 = 0; fm8 < 8; ++fm8) {
#pragma unroll
    for (int r = 0; r < 4; ++r) {
      float s = 0.f;
#pragma unroll
      for (int fn = 0; fn < 4; ++fn)
        s += v_n[fn] * fast_tanh(acc[fm8][fn][r] + a_n[fn]);
      s += __shfl_xor(s, 1);
      s += __shfl_xor(s, 2);
      s += __shfl_xor(s, 4);
      s += __shfl_xor(s, 8);
      if (lr == 0) red4[wn][wm * 128 + fm8 * 16 + lk * 4 + r] = s;
    }
  }
  __syncthreads();
  if (tid < 256) {
    const float ssum = red4[0][tid] + red4[1][tid] + red4[2][tid] + red4[3][tid];
    sp[(size_t)nblk * MTOT + m0 + tid] = ssum;
  }
}

// ---- softmax over s (512) per b; sums 4 partials ----
__global__ __launch_bounds__(512) void softmax4_kernel(const float* __restrict__ sp,
                                                       float* __restrict__ wts) {
  const int b = blockIdx.x, s = threadIdx.x;
  float sc = 0.f;
#pragma unroll
  for (int j = 0; j < 4; ++j) sc += sp[(size_t)j * MTOT + b * SDIM + s];
  float m = sc;
#pragma unroll
  for (int d = 1; d < 64; d <<= 1) m = fmaxf(m, __shfl_xor(m, d));
  __shared__ float redm[8], reds[8];
  if ((s & 63) == 0) redm[s >> 6] = m;
  __syncthreads();
  m = redm[0];
#pragma unroll
  for (int j = 1; j < 8; ++j) m = fmaxf(m, redm[j]);
  const float e = expf(sc - m);
  float sum = e;
#pragma unroll
  for (int d = 1; d < 64; d <<= 1) sum += __shfl_xor(sum, d);
  if ((s & 63) == 0) reds[s >> 6] = sum;
  __syncthreads();
  float tot = 0.f;
#pragma unroll
  for (int j = 0; j < 8; ++j) tot += reds[j];
  wts[(size_t)b * SDIM + s] = e / tot;
}

// ---- context[b,h] = sum_s w[b,s] * enc[b,s,h] ----
__global__ __launch_bounds__(256) void context_kernel(const float* __restrict__ enc,
                                                      const float* __restrict__ wts,
                                                      float* __restrict__ ctx) {
  const int hc = blockIdx.x;
  const int b  = blockIdx.y;
  const int t  = threadIdx.x;
  __shared__ float wl[SDIM];
  wl[t] = wts[(size_t)b * SDIM + t];
  wl[t + 256] = wts[(size_t)b * SDIM + 256 + t];
  __syncthreads();
  const int h = hc * 256 + t;
  const float* e0 = enc + (size_t)b * SDIM * HDIM + h;
  float acc0 = 0.f, acc1 = 0.f;
  for (int s = 0; s < SDIM; s += 2) {
    acc0 += wl[s] * e0[(size_t)s * HDIM];
    acc1 += wl[s + 1] * e0[(size_t)(s + 1) * HDIM];
  }
  ctx[(size_t)b * HDIM + h] = acc0 + acc1;
}

extern "C" void kernel_launch(void* const* d_in, const int* in_sizes, int n_in,
                              void* d_out, int out_size, void* d_ws, size_t ws_size,
                              hipStream_t stream) {
  const float* hidden = (const float*)d_in[0];
  const float* enc    = (const float*)d_in[1];
  const float* W      = (const float*)d_in[2];
  const float* bias   = (const float*)d_in[3];
  const float* v      = (const float*)d_in[4];

  float* ctx = (float*)d_out;                // [64*1024] context
  float* wts = (float*)d_out + BDIM * HDIM;  // [64*512] attention weights

  char* ws = (char*)d_ws;
  char* w2s = ws;                                                   // 2 MB swizzled W2 tiles
  float* A  = (float*)(ws + (size_t)2 * 1024 * 1024);               // 256 KB
  float* sp = (float*)(ws + (size_t)2 * 1024 * 1024 + 256 * 1024);  // 512 KB (4 partials)

  hipLaunchKernelGGL(prep_w2_kernel, dim3(512), dim3(256), 0, stream, W, w2s);
  hipLaunchKernelGGL(compute_a_kernel, dim3(4, 64), dim3(256), 0, stream, hidden, W, bias, A);
  hipLaunchKernelGGL(gemm8f_kernel, dim3(512), dim3(512), 0, stream, enc, w2s, A, v, sp);
  hipLaunchKernelGGL(softmax4_kernel, dim3(64), dim3(512), 0, stream, sp, wts);
  hipLaunchKernelGGL(context_kernel, dim3(4, 64), dim3(256), 0, stream, enc, wts, ctx);
}